// Round 6
// baseline (607.591 us; speedup 1.0000x reference)
//
#include <hip/hip_runtime.h>

#define NN 131072
#define NE 2097152
#define DD 128
#define LL 3

#define NB 256      // partition buckets
#define BSH 9       // log2(nodes per bucket) -> 512 nodes/bucket
#define TILE (NE / NB)   // 8192 edges per pass-A block

typedef __attribute__((ext_vector_type(8))) short short8;
typedef __attribute__((ext_vector_type(4))) float f32x4;

__device__ __forceinline__ ushort f2bf(float f) {
    uint u = __float_as_uint(f);
    return (ushort)((u + 0x7fffu + ((u >> 16) & 1u)) >> 16);   // RNE
}
__device__ __forceinline__ float bflo(uint u) { return __uint_as_float(u << 16); }
__device__ __forceinline__ float bfhi(uint u) { return __uint_as_float(u & 0xffff0000u); }

// ---------------- misc init ----------------
__global__ __launch_bounds__(256) void k_zero(float* __restrict__ bns) {
    int i = blockIdx.x * 256 + threadIdx.x;
    if (i < 768) bns[i] = 0.0f;
}

// ---------------- Pass A: bucket histogram per block ----------------
__global__ __launch_bounds__(256) void kA_count(const int* __restrict__ tgt,
                                                int* __restrict__ blockHist) {
    __shared__ int hist[NB];
    const int t = threadIdx.x, blk = blockIdx.x;
    hist[t] = 0;
    __syncthreads();
    const int base = blk * TILE;
#pragma unroll 8
    for (int j = 0; j < TILE / 256; ++j)
        atomicAdd(&hist[tgt[base + j * 256 + t] >> BSH], 1);
    __syncthreads();
    blockHist[t * NB + blk] = hist[t];   // bucket-major
}

// ---------------- Pass A scan: chunk bases (absolute) + bucket starts --------
__global__ __launch_bounds__(256) void kA_scan(int* __restrict__ blockHist,
                                               int* __restrict__ bstart) {
    __shared__ int part[NB];
    const int t = threadIdx.x;
    int4* bh = (int4*)(blockHist + t * NB);
    int run = 0;
    int4 tmp[NB / 4];
#pragma unroll 8
    for (int j = 0; j < NB / 4; ++j) tmp[j] = bh[j];
#pragma unroll 8
    for (int j = 0; j < NB / 4; ++j) {
        int4 v = tmp[j];
        int a = run; run += v.x;
        int b = run; run += v.y;
        int c = run; run += v.z;
        int d = run; run += v.w;
        tmp[j] = make_int4(a, b, c, d);
    }
    part[t] = run;                       // bucket size
    __syncthreads();
    for (int off = 1; off < NB; off <<= 1) {
        int v = part[t];
        int u = (t >= off) ? part[t - off] : 0;
        __syncthreads();
        part[t] = v + u;
        __syncthreads();
    }
    const int excl = part[t] - run;      // exclusive bucket start
    bstart[t] = excl;
    if (t == NB - 1) bstart[NB] = part[t];
#pragma unroll 8
    for (int j = 0; j < NB / 4; ++j) {
        int4 v = tmp[j];
        bh[j] = make_int4(v.x + excl, v.y + excl, v.z + excl, v.w + excl);
    }
}

// ---------------- Pass A scatter: packed = src | tgt_local<<17 ---------------
__global__ __launch_bounds__(256) void kA_scatter(const int* __restrict__ src,
                                                  const int* __restrict__ tgt,
                                                  const int* __restrict__ chunkBase,
                                                  uint* __restrict__ packed) {
    __shared__ int cur[NB];
    const int t = threadIdx.x, blk = blockIdx.x;
    cur[t] = chunkBase[t * NB + blk];
    __syncthreads();
    const int base = blk * TILE;
#pragma unroll 4
    for (int j = 0; j < TILE / 256; ++j) {
        const int e = base + j * 256 + t;
        const int tg = tgt[e], s = src[e];
        const int b = tg >> BSH;
        const int pos = atomicAdd(&cur[b], 1);
        packed[pos] = (uint)s | ((uint)(tg & ((1 << BSH) - 1)) << 17);
    }
}

// ---------------- Pass B: per-bucket counting sort -> rowp, dinv, ssrc -------
__global__ __launch_bounds__(256) void kB_sort(const uint* __restrict__ packed,
                                               const int* __restrict__ bstart,
                                               int* __restrict__ rowp,
                                               float* __restrict__ dinv,
                                               int* __restrict__ ssrc) {
    __shared__ int cnt[1 << BSH];
    __shared__ int pscan[256];
    const int t = threadIdx.x, b = blockIdx.x;
    const int e0 = bstart[b], e1 = bstart[b + 1];
    cnt[t] = 0; cnt[t + 256] = 0;
    __syncthreads();
    for (int e = e0 + t; e < e1; e += 256)
        atomicAdd(&cnt[packed[e] >> 17], 1);
    __syncthreads();
    const int c0 = cnt[2 * t], c1 = cnt[2 * t + 1];
    pscan[t] = c0 + c1;
    __syncthreads();
    for (int off = 1; off < 256; off <<= 1) {
        int v = pscan[t];
        int u = (t >= off) ? pscan[t - off] : 0;
        __syncthreads();
        pscan[t] = v + u;
        __syncthreads();
    }
    const int ex0 = pscan[t] - c0 - c1;
    const int ex1 = ex0 + c0;
    const int n0 = (b << BSH) + 2 * t;
    rowp[n0] = e0 + ex0;
    rowp[n0 + 1] = e0 + ex1;
    dinv[n0] = rsqrtf((float)(c0 + 1));
    dinv[n0 + 1] = rsqrtf((float)(c1 + 1));
    if (b == NB - 1 && t == 255) rowp[NN] = e1;
    __syncthreads();
    cnt[2 * t] = ex0;
    cnt[2 * t + 1] = ex1;
    __syncthreads();
    for (int e = e0 + t; e < e1; e += 256) {
        const uint p = packed[e];
        const int pos = atomicAdd(&cnt[p >> 17], 1);
        ssrc[e0 + pos] = (int)(p & 0x1FFFFu);
    }
}

// ---------------- weight transpose+convert: wt[m][c][k] = bf16(W_m[k][c]) ----
__global__ __launch_bounds__(256) void k_prepw(const float* __restrict__ Wi,
                                               const float* __restrict__ Wg,
                                               const float* __restrict__ Wr,
                                               ushort* __restrict__ wt) {
    const int id = blockIdx.x * 256 + threadIdx.x;   // 7*16384
    const int m = id >> 14;
    const int c = (id >> 7) & 127;
    const int k = id & 127;
    float v;
    if (m == 0)      v = (k < 74) ? Wi[k * DD + c] : 0.0f;
    else if (m <= 3) v = Wg[(size_t)(m - 1) * DD * DD + k * DD + c];
    else             v = Wr[(size_t)(m - 4) * DD * DD + k * DD + c];
    wt[id] = f2bf(v);
}

// ---------------- x f32[NN][74] -> bf16[NN][128] zero-padded ----------------
__global__ __launch_bounds__(256) void k_convx(const float* __restrict__ x,
                                               uint* __restrict__ xb) {
    const size_t id = (size_t)blockIdx.x * 256 + threadIdx.x;   // NN*64
    const int n = (int)(id >> 6);
    const int k0 = (int)(id & 63) * 2;
    float v0 = (k0 < 74) ? x[(size_t)n * 74 + k0] : 0.0f;
    float v1 = (k0 + 1 < 74) ? x[(size_t)n * 74 + k0 + 1] : 0.0f;
    xb[id] = (uint)f2bf(v0) | ((uint)f2bf(v1) << 16);
}

// ---------------- MFMA GEMM: [N,128] @ Wt^T ----------------
// MODE 0: outb = bf16(acc)                                   (init transform)
// MODE 1: outb = bf16(acc) (conv) + column sum/sumsq(f32) -> bnsums (GCN gemm)
// MODE 2: outb = bf16(relu(conv*sc+sh) + acc + bres)         (fused residual)
// MODE 3: MODE 2 + outf = f32 value (final output)
template <int MODE>
__global__ __launch_bounds__(256) void k_mgemm(const ushort* A,
                                               const ushort* __restrict__ Bt,
                                               ushort* outb,
                                               float* __restrict__ outf,
                                               const ushort* __restrict__ convb,
                                               const float* __restrict__ ss,
                                               const float* __restrict__ bres,
                                               float* __restrict__ bnsums) {
    __shared__ ushort As[16384];   // 128 rows x 128 k, XOR-swizzled, 32KB
    __shared__ ushort Bs[16384];
    __shared__ float sred[256];
    const int t = threadIdx.x;
    const int w = t >> 6, l = t & 63;
    const int lc = l & 15, lr = l >> 4;
    const size_t row0 = (size_t)blockIdx.x * 128;

    for (int ch = w * 8; ch < w * 8 + 8; ++ch) {
        const int row = ch * 4 + lr;
        const int kb = (lc * 16) ^ ((row & 7) << 4);
        const ushort* srcA = A + (row0 + row) * DD + (kb >> 1);
        const ushort* srcB = Bt + (size_t)row * DD + (kb >> 1);
        __builtin_amdgcn_global_load_lds(
            (const __attribute__((address_space(1))) void*)srcA,
            (__attribute__((address_space(3))) void*)(As + ch * 512), 16, 0, 0);
        __builtin_amdgcn_global_load_lds(
            (const __attribute__((address_space(1))) void*)srcB,
            (__attribute__((address_space(3))) void*)(Bs + ch * 512), 16, 0, 0);
    }
    if (MODE == 1) sred[t] = 0.0f;
    __syncthreads();

    f32x4 acc[2][8] = {};
    const char* Ab = (const char*)As;
    const char* Bb = (const char*)Bs;
#pragma unroll
    for (int kk = 0; kk < 4; ++kk) {
        const int kb = kk * 64 + lr * 16;
        short8 a[2];
#pragma unroll
        for (int m = 0; m < 2; ++m) {
            const int r = w * 32 + m * 16 + lc;
            a[m] = *(const short8*)(Ab + r * 256 + (kb ^ ((r & 7) << 4)));
        }
#pragma unroll
        for (int n = 0; n < 8; ++n) {
            const int c = n * 16 + lc;
            short8 b = *(const short8*)(Bb + c * 256 + (kb ^ ((c & 7) << 4)));
            acc[0][n] = __builtin_amdgcn_mfma_f32_16x16x32_bf16(a[0], b, acc[0][n], 0, 0, 0);
            acc[1][n] = __builtin_amdgcn_mfma_f32_16x16x32_bf16(a[1], b, acc[1][n], 0, 0, 0);
        }
    }

    if (MODE == 0) {
#pragma unroll
        for (int m = 0; m < 2; ++m)
#pragma unroll
            for (int n = 0; n < 8; ++n) {
                const int c = n * 16 + lc;
#pragma unroll
                for (int j = 0; j < 4; ++j) {
                    const size_t r = row0 + w * 32 + m * 16 + lr * 4 + j;
                    outb[r * DD + c] = f2bf(acc[m][n][j]);
                }
            }
    } else if (MODE == 1) {
#pragma unroll
        for (int n = 0; n < 8; ++n) {
            const int c = n * 16 + lc;
            float ps = 0.0f, ps2 = 0.0f;
#pragma unroll
            for (int m = 0; m < 2; ++m)
#pragma unroll
                for (int j = 0; j < 4; ++j) {
                    const size_t r = row0 + w * 32 + m * 16 + lr * 4 + j;
                    const float v = acc[m][n][j];
                    outb[r * DD + c] = f2bf(v);
                    ps += v; ps2 += v * v;
                }
            atomicAdd(&sred[c], ps);
            atomicAdd(&sred[DD + c], ps2);
        }
        __syncthreads();
        atomicAdd(&bnsums[t], sred[t]);
    } else {
        float scv[8], shv[8], bbv[8];
#pragma unroll
        for (int n = 0; n < 8; ++n) {
            const int c = n * 16 + lc;
            scv[n] = ss[c]; shv[n] = ss[DD + c]; bbv[n] = bres[c];
        }
#pragma unroll
        for (int m = 0; m < 2; ++m)
#pragma unroll
            for (int n = 0; n < 8; ++n) {
                const int c = n * 16 + lc;
#pragma unroll
                for (int j = 0; j < 4; ++j) {
                    const size_t r = row0 + w * 32 + m * 16 + lr * 4 + j;
                    const float cv = __uint_as_float((uint)convb[r * DD + c] << 16);
                    const float v = fmaxf(cv * scv[n] + shv[n], 0.0f) + acc[m][n][j] + bbv[n];
                    outb[r * DD + c] = f2bf(v);
                    if (MODE == 3) outf[r * DD + c] = v;
                }
            }
    }
}

// ---------------- CSR aggregate: 4 rows per dwordx4 gather instruction -------
// wave: 4 groups x 16 lanes; group g handles edge (i+g), lane owns 8 columns.
// aggb[n] = bf16( dinv[n]^2*hb[n] + sum_e dinv[n]dinv[s]*hb[s] )
__global__ __launch_bounds__(256) void k_aggregate(const int* __restrict__ row,
                                                   const int* __restrict__ ssrc,
                                                   const float* __restrict__ dinv,
                                                   const uint* __restrict__ hb,
                                                   uint* __restrict__ aggb) {
    const int n = blockIdx.x * 4 + (threadIdx.x >> 6);
    const int l = threadIdx.x & 63;
    const int g = l >> 4;          // group
    const int sub = l & 15;        // owns cols sub*8 .. sub*8+7
    const float dn = dinv[n];

    float acc[8];
    {   // self term (group 0 only; others init 0)
        const uint4 v = *(const uint4*)(hb + ((size_t)n << 6) + sub * 4);
        const float dn2 = (g == 0) ? dn * dn : 0.0f;
        acc[0] = dn2 * bflo(v.x); acc[1] = dn2 * bfhi(v.x);
        acc[2] = dn2 * bflo(v.y); acc[3] = dn2 * bfhi(v.y);
        acc[4] = dn2 * bflo(v.z); acc[5] = dn2 * bfhi(v.z);
        acc[6] = dn2 * bflo(v.w); acc[7] = dn2 * bfhi(v.w);
    }

    const int e0 = row[n], e1 = row[n + 1];
    for (int base = e0; base < e1; base += 64) {
        const int cnt = min(64, e1 - base);
        int sv = 0; float dv = 0.0f;
        if (l < cnt) { sv = ssrc[base + l]; dv = dinv[sv] * dn; }
        for (int i = 0; i < cnt; i += 16) {    // 16 edges per sweep, 4/instr
            uint4 vv[4]; float nm[4];
#pragma unroll
            for (int j = 0; j < 4; ++j) {
                const int e = i + j * 4 + g;             // <= 63 always
                const int s = __shfl(sv, e);             // pad: s=0, nm=0
                nm[j] = __shfl(dv, e);
                vv[j] = *(const uint4*)(hb + ((size_t)s << 6) + sub * 4);
            }
#pragma unroll
            for (int j = 0; j < 4; ++j) {
                acc[0] += nm[j] * bflo(vv[j].x); acc[1] += nm[j] * bfhi(vv[j].x);
                acc[2] += nm[j] * bflo(vv[j].y); acc[3] += nm[j] * bfhi(vv[j].y);
                acc[4] += nm[j] * bflo(vv[j].z); acc[5] += nm[j] * bfhi(vv[j].z);
                acc[6] += nm[j] * bflo(vv[j].w); acc[7] += nm[j] * bfhi(vv[j].w);
            }
        }
    }

    // combine the 4 groups (lanes l, l^16, l^32, l^48 hold same columns)
#pragma unroll
    for (int k = 0; k < 8; ++k) {
        acc[k] += __shfl_xor(acc[k], 16);
        acc[k] += __shfl_xor(acc[k], 32);
    }
    if (g == 0) {
        uint4 o;
        o.x = (uint)f2bf(acc[0]) | ((uint)f2bf(acc[1]) << 16);
        o.y = (uint)f2bf(acc[2]) | ((uint)f2bf(acc[3]) << 16);
        o.z = (uint)f2bf(acc[4]) | ((uint)f2bf(acc[5]) << 16);
        o.w = (uint)f2bf(acc[6]) | ((uint)f2bf(acc[7]) << 16);
        *(uint4*)(aggb + ((size_t)n << 6) + sub * 4) = o;
    }
}

// ---------------- BN finalize ----------------
__global__ void k_bnfin(const float* __restrict__ sums,
                        const float* __restrict__ gamma,
                        const float* __restrict__ beta,
                        float* __restrict__ ss) {
    int c = threadIdx.x;
    const float invN = 1.0f / (float)NN;
    float mean = sums[c] * invN;
    float var = sums[DD + c] * invN - mean * mean;
    float sc = gamma[c] * rsqrtf(var + 1e-5f);
    ss[c] = sc;
    ss[DD + c] = beta[c] - mean * sc;
}

// ---------------- launch ----------------
extern "C" void kernel_launch(void* const* d_in, const int* in_sizes, int n_in,
                              void* d_out, int out_size, void* d_ws, size_t ws_size,
                              hipStream_t stream) {
    const float* x      = (const float*)d_in[0];
    const int*   ei     = (const int*)d_in[1];
    const float* W_init = (const float*)d_in[3];
    const float* W_gcn  = (const float*)d_in[4];
    const float* gamma  = (const float*)d_in[6];
    const float* beta   = (const float*)d_in[7];
    const float* W_res  = (const float*)d_in[8];
    const float* b_res  = (const float*)d_in[9];

    float* h = (float*)d_out;
    char* p = (char*)d_ws;
    ushort* aggb = (ushort*)p;           p += (size_t)NN * DD * 2;   // 32MB
    ushort* hb   = (ushort*)p;           p += (size_t)NN * DD * 2;   // 32MB
    ushort* convb = (ushort*)p;          p += (size_t)NN * DD * 2;   // 32MB
    uint*   xb   = (uint*)convb;         // aliases convb: dead before conv write
    float*  dinv = (float*)p;            p += (size_t)NN * 4;
    float*  bns  = (float*)p;            p += 768 * 4;
    float*  ss   = (float*)p;            p += 256 * 4;
    ushort* wt   = (ushort*)p;           p += 7 * 16384 * 2;
    int* blockHist = (int*)p;            p += (size_t)NB * NB * 4;
    int* bstart  = (int*)p;              p += (NB + 1) * 4 + 4;
    uint* packed = (uint*)p;             p += (size_t)NE * 4;
    int* rowp    = (int*)p;              p += ((size_t)NN + 1) * 4 + 4;
    int* ssrc    = (int*)p;

    const int* srcp = ei;
    const int* tgtp = ei + NE;

    k_zero<<<3, 256, 0, stream>>>(bns);
    kA_count<<<NB, 256, 0, stream>>>(tgtp, blockHist);
    kA_scan<<<1, 256, 0, stream>>>(blockHist, bstart);
    kA_scatter<<<NB, 256, 0, stream>>>(srcp, tgtp, blockHist, packed);
    kB_sort<<<NB, 256, 0, stream>>>(packed, bstart, rowp, dinv, ssrc);

    k_prepw<<<7 * 16384 / 256, 256, 0, stream>>>(W_init, W_gcn, W_res, wt);
    k_convx<<<NN * 64 / 256, 256, 0, stream>>>(x, xb);

    k_mgemm<0><<<NN / 128, 256, 0, stream>>>((const ushort*)xb, wt, hb,
                                             nullptr, nullptr, nullptr, nullptr, nullptr);

    for (int i = 0; i < LL; ++i) {
        k_aggregate<<<NN / 4, 256, 0, stream>>>(rowp, ssrc, dinv,
                                                (const uint*)hb, (uint*)aggb);
        k_mgemm<1><<<NN / 128, 256, 0, stream>>>(aggb, wt + (size_t)(1 + i) * 16384,
                                                 convb, nullptr, nullptr, nullptr,
                                                 nullptr, bns + i * 256);
        k_bnfin<<<1, 128, 0, stream>>>(bns + i * 256, gamma + i * DD,
                                       beta + i * DD, ss);
        if (i < LL - 1)
            k_mgemm<2><<<NN / 128, 256, 0, stream>>>(hb, wt + (size_t)(4 + i) * 16384,
                                                     hb, nullptr, convb, ss,
                                                     b_res + i * DD, nullptr);
        else
            k_mgemm<3><<<NN / 128, 256, 0, stream>>>(hb, wt + (size_t)(4 + i) * 16384,
                                                     hb, h, convb, ss,
                                                     b_res + i * DD, nullptr);
    }
}